// Round 12
// baseline (310.346 us; speedup 1.0000x reference)
//
#include <hip/hip_runtime.h>

// NeurTWs R21: the pre-committed 32-rows/wave restructure. R20 refuted
// the coalesced store (WRITE 11->13.3MB, 57us -- L2 already line-
// coalesced the masked stores; LDS staging was pure overhead): R17
// epilogue restored. Why R21: all four 4-wave attempts (R11/R13/R15/R19)
// spilled because the 64-row/wave body NEEDS ~148 regs (fA 32 + a_h 16 +
// pc 32 + acc 64 AGPR + ~50 persist). Halving the per-wave tile halves
// exactly the big terms: acc 32 AGPR, fA 16, pc 16, a_h 8 -> est 60-75
// arch + 32 AGPR <= 128 -> 4 waves/SIMD honestly. Structure:
//  - block 256 thr = 4 waves x 32 rows; block-iter = 128 rows; GRID 1024
//    x 8 iters = 1M rows EXACTLY (zero tail; also kills the 6-vs-5.33
//    iter quantization that cost ~7% at grid 768).
//  - LDS: hpe 128x40x2=10KB + wm1t 13KB = 23KB; 4 blocks/CU = 94KB OK.
//  - GEMM1 split 2 lanes/row (jh=lane>>5 handles 16 of 32 j's);
//    duplicate enc loads hit the same line (free).
//  - R17 prefetch pipeline at half scale: deep fA0 cross-iter (8 regs),
//    fA1 iter-top, ndr_n/kk_n/enc_n prefetch. R17 masked-store epilogue.
//  - launch_bounds(256,4): cap 96 arch (128-32 AGPR); body est 60-75.
// DECISIVE: WRITE ~11MB = no spill. Pre-commit: (a) WRITE>>15MB = the
// 32-row body still spills -> revert R17, declare; (b) no spill but
// >=54us -> wave->BW scaling fails for gather traffic -> R17 is the
// equilibrium, declare roofline.
// Fragment layouts (gfx950, verified): A/B: idx=lane&15, k=(lane>>4)*8+j;
// C/D: col=lane&15, row=(lane>>4)*4+reg.

typedef _Float16 half8 __attribute__((ext_vector_type(8)));
typedef float floatx4 __attribute__((ext_vector_type(4)));

#define HSTR 40    // h/pe row stride (f16): 80 B
#define WSTR 104   // wm1t row stride (f16): 208 B
#define GRID_MAIN 1024
#define IT_ROWS (GRID_MAIN * 128)

__global__ void feat_to_f16(const float* __restrict__ nf,
                            _Float16* __restrict__ o, int n8) {
    int t = blockIdx.x * 256 + threadIdx.x;
    if (t >= n8) return;
    const float4* p = (const float4*)nf + (size_t)t * 2;
    const float4 a = p[0], b = p[1];
    half8 h;
    h[0] = (_Float16)a.x; h[1] = (_Float16)a.y;
    h[2] = (_Float16)a.z; h[3] = (_Float16)a.w;
    h[4] = (_Float16)b.x; h[5] = (_Float16)b.y;
    h[6] = (_Float16)b.z; h[7] = (_Float16)b.w;
    *((half8*)o + t) = h;
}

// load feat A-fragments for ONE 16-row tile (2 half8 = 8 VGPR)
__device__ __forceinline__ void load_feat1(const _Float16* __restrict__ feat16,
                                           const float* __restrict__ node_feat,
                                           int use_f16, int nd, int q,
                                           half8 fA[2]) {
    if (use_f16) {
        const _Float16* fb = feat16 + (size_t)nd * 64 + q * 8;
        fA[0] = *(const half8*)(fb);
        fA[1] = *(const half8*)(fb + 32);
    } else {
        const float* fb = node_feat + (size_t)nd * 64 + q * 8;
        #pragma unroll
        for (int kt = 0; kt < 2; ++kt) {
            const float4 lo = *(const float4*)(fb + kt * 32);
            const float4 hi = *(const float4*)(fb + kt * 32 + 4);
            half8 h;
            h[0] = (_Float16)lo.x; h[1] = (_Float16)lo.y;
            h[2] = (_Float16)lo.z; h[3] = (_Float16)lo.w;
            h[4] = (_Float16)hi.x; h[5] = (_Float16)hi.y;
            h[6] = (_Float16)hi.z; h[7] = (_Float16)hi.w;
            fA[kt] = h;
        }
    }
}

__global__ __launch_bounds__(256, 4) void neurtw_r21(
    const float* __restrict__ pos_table,   // [NUM_KEYS, 4]
    const float* __restrict__ node_feat,   // [NUM_NODES, 64] fp32 (fallback)
    const float* __restrict__ W1,          // [4, 32]
    const float* __restrict__ b1,          // [32]
    const float* __restrict__ W2,          // [32, 32]
    const float* __restrict__ b2,          // [32]
    const float* __restrict__ Wm1,         // [96, 64]
    const float* __restrict__ bm1,         // [64]
    const float* __restrict__ Wm2,         // [64, 1]
    const float* __restrict__ bm2,         // [1]
    const int*   __restrict__ key_idx,     // [rows]
    const int*   __restrict__ node_idx,    // [rows]
    const _Float16* __restrict__ feat16,   // [NUM_NODES, 64] f16 (ws)
    int use_f16,
    float*       __restrict__ out,         // [rows]
    int rows)
{
    __shared__ _Float16 hpe[128 * HSTR];   // 10 KB (h then pe; wave-private)
    __shared__ _Float16 wm1t[64 * WSTR];   // 13 KB  wm1t[n][k] = Wm1[k][n]

    const int tid  = threadIdx.x;
    const int lane = tid & 63;
    const int wr0  = (tid >> 6) * 32;      // wave's 32-row slice base
    const int ln   = lane & 15;
    const int q    = lane >> 4;
    const int rloc = lane & 31;            // row within wave slice
    const int jh   = lane >> 5;            // GEMM1 j-half (0/1)

    // ---------- once per block: stage Wm1^T into LDS ----------
    #pragma unroll
    for (int i = 0; i < 3; ++i) {
        const int task = i * 256 + tid;
        const int n = task & 63, k8 = task >> 6;
        half8 w;
        #pragma unroll
        for (int kk = 0; kk < 8; ++kk)
            w[kk] = (_Float16)Wm1[(k8 * 8 + kk) * 64 + n];
        *(half8*)(&wm1t[n * WSTR + k8 * 8]) = w;
    }

    // ---------- once per block: per-lane weight/bias fragments ----------
    half8 b_w2[2];
    #pragma unroll
    for (int ct = 0; ct < 2; ++ct)
        #pragma unroll
        for (int j = 0; j < 8; ++j)
            b_w2[ct][j] = (_Float16)W2[(q * 8 + j) * 32 + ct * 16 + ln];
    float b2v[2];
    b2v[0] = b2[ln]; b2v[1] = b2[16 + ln];
    float bm1v[4], wm2v[4];
    #pragma unroll
    for (int ct = 0; ct < 4; ++ct) {
        bm1v[ct] = bm1[ct * 16 + ln];
        wm2v[ct] = Wm2[ct * 16 + ln];
    }
    const float bm2s = bm2[0];

    __syncthreads();   // wm1t staged (the ONLY barrier in the kernel)

    // ---------- pipeline prologue: iter-0 indices + enc + fA0 ----------
    int base = blockIdx.x * 128;           // block-iter covers 128 rows
    int ndr[2];
    #pragma unroll
    for (int rt = 0; rt < 2; ++rt)
        ndr[rt] = node_idx[base + wr0 + rt * 16 + ln];
    int kkc = key_idx[base + wr0 + rloc];
    float4 enc = *(const float4*)(pos_table + (size_t)kkc * 4);
    half8 fA0[2];
    load_feat1(feat16, node_feat, use_f16, ndr[0], q, fA0);

    while (base < rows) {
        const int nbase = base + IT_ROWS;
        const bool more = nbase < rows;

        // ---- iter top: the rt=1 feat gather (ndr resident) ----
        half8 fA1[2];
        load_feat1(feat16, node_feat, use_f16, ndr[1], q, fA1);

        // ---- next-iter independent index loads ----
        int ndr_n[2];
        int kk_n;
        if (more) {
            #pragma unroll
            for (int rt = 0; rt < 2; ++rt)
                ndr_n[rt] = node_idx[nbase + wr0 + rt * 16 + ln];
            kk_n = key_idx[nbase + wr0 + rloc];
        } else {
            ndr_n[0] = 0; ndr_n[1] = 0;
            kk_n = 0;
        }

        // ---- GEMM1 (VALU fp32, enc resident; 2 lanes/row, 16 j each) ----
        const int hrow = wr0 + rloc;
        #pragma unroll
        for (int g = 0; g < 2; ++g) {
            half8 hv;
            #pragma unroll
            for (int j8 = 0; j8 < 8; ++j8) {
                const int j = jh * 16 + g * 8 + j8;
                float a = fmaf(enc.w, W1[96 + j],
                          fmaf(enc.z, W1[64 + j],
                          fmaf(enc.y, W1[32 + j],
                          fmaf(enc.x, W1[j], b1[j]))));
                hv[j8] = (_Float16)fmaxf(a, 0.0f);
            }
            *(half8*)(&hpe[hrow * HSTR + jh * 16 + g * 8]) = hv;
        }
        // wave-private transpose read — no barrier (same wave wrote it)
        half8 a_h[2];
        #pragma unroll
        for (int rt = 0; rt < 2; ++rt)
            a_h[rt] = *(const half8*)(&hpe[(wr0 + rt * 16 + ln) * HSTR + q * 8]);

        // ---- GEMM2: 4 MFMA -> pe (C-layout regs) ----
        floatx4 pc[2][2];
        #pragma unroll
        for (int rt = 0; rt < 2; ++rt)
            #pragma unroll
            for (int ct = 0; ct < 2; ++ct) {
                floatx4 c = {0.f, 0.f, 0.f, 0.f};
                pc[rt][ct] = __builtin_amdgcn_mfma_f32_16x16x32_f16(
                    a_h[rt], b_w2[ct], c, 0, 0, 0);
            }

        // write pe into the SAME buffer (h consumed; own wave's slice only)
        #pragma unroll
        for (int rt = 0; rt < 2; ++rt)
            #pragma unroll
            for (int ct = 0; ct < 2; ++ct)
                #pragma unroll
                for (int r = 0; r < 4; ++r)
                    hpe[(wr0 + rt * 16 + q * 4 + r) * HSTR + ct * 16 + ln] =
                        (_Float16)(pc[rt][ct][r] + b2v[ct]);
        // no barrier: reader below is the same wave

        // ---- next-iter enc gather (kk_n has had GEMM1+GEMM2 to land) ----
        float4 enc_n = enc;
        if (more)
            enc_n = *(const float4*)(pos_table + (size_t)kk_n * 4);

        // ---- GEMM3: 24 MFMA ----
        floatx4 acc[2][4];
        #pragma unroll
        for (int ct = 0; ct < 4; ++ct) {
            const float bb = bm1v[ct];
            acc[0][ct] = (floatx4){bb, bb, bb, bb};
            acc[1][ct] = (floatx4){bb, bb, bb, bb};
        }

        {   // ktile 0: A = pe from LDS
            half8 a_pe[2];
            #pragma unroll
            for (int rt = 0; rt < 2; ++rt)
                a_pe[rt] = *(const half8*)(&hpe[(wr0 + rt * 16 + ln) * HSTR + q * 8]);
            half8 b0[4];
            #pragma unroll
            for (int ct = 0; ct < 4; ++ct)
                b0[ct] = *(const half8*)(&wm1t[(ct * 16 + ln) * WSTR + q * 8]);
            #pragma unroll
            for (int rt = 0; rt < 2; ++rt)
                #pragma unroll
                for (int ct = 0; ct < 4; ++ct)
                    acc[rt][ct] = __builtin_amdgcn_mfma_f32_16x16x32_f16(
                        a_pe[rt], b0[ct], acc[rt][ct], 0, 0, 0);
        }

        #pragma unroll
        for (int kt = 0; kt < 2; ++kt) {   // ktiles 1,2: A = feat
            half8 bk[4];
            #pragma unroll
            for (int ct = 0; ct < 4; ++ct)
                bk[ct] = *(const half8*)(&wm1t[(ct * 16 + ln) * WSTR + 32 + kt * 32 + q * 8]);
            #pragma unroll
            for (int ct = 0; ct < 4; ++ct) {
                acc[0][ct] = __builtin_amdgcn_mfma_f32_16x16x32_f16(
                    fA0[kt], bk[ct], acc[0][ct], 0, 0, 0);
                acc[1][ct] = __builtin_amdgcn_mfma_f32_16x16x32_f16(
                    fA1[kt], bk[ct], acc[1][ct], 0, 0, 0);
            }
        }

        // ---- fA consumed: deep-prefetch NEXT-iter fA0 (rt 0) now ----
        // ndr_n arrived ~1 iter ago; cover = GEMM4 + next GEMM1/2.
        half8 fA0_n[2];
        load_feat1(feat16, node_feat, use_f16, ndr_n[0], q, fA0_n);

        // ---- GEMM4: relu + Wm2 dot + 4-step butterfly + store ----
        #pragma unroll
        for (int rt = 0; rt < 2; ++rt) {
            #pragma unroll
            for (int r = 0; r < 4; ++r) {
                float p = 0.0f;
                #pragma unroll
                for (int ct = 0; ct < 4; ++ct)
                    p = fmaf(fmaxf(acc[rt][ct][r], 0.0f), wm2v[ct], p);
                p += __shfl_xor(p, 1);
                p += __shfl_xor(p, 2);
                p += __shfl_xor(p, 4);
                p += __shfl_xor(p, 8);
                if (ln == 0)
                    out[base + wr0 + rt * 16 + q * 4 + r] = p + bm2s;
            }
        }

        // ---- rotate pipeline state ----
        base = nbase;
        ndr[0] = ndr_n[0];
        ndr[1] = ndr_n[1];
        kkc = kk_n;
        enc = enc_n;
        fA0[0] = fA0_n[0];
        fA0[1] = fA0_n[1];
    }
}

extern "C" void kernel_launch(void* const* d_in, const int* in_sizes, int n_in,
                              void* d_out, int out_size, void* d_ws, size_t ws_size,
                              hipStream_t stream) {
    const float* pos_table = (const float*)d_in[0];
    const float* node_feat = (const float*)d_in[1];
    const float* W1        = (const float*)d_in[2];
    const float* b1        = (const float*)d_in[3];
    const float* W2        = (const float*)d_in[4];
    const float* b2        = (const float*)d_in[5];
    const float* Wm1       = (const float*)d_in[6];
    const float* bm1       = (const float*)d_in[7];
    const float* Wm2       = (const float*)d_in[8];
    const float* bm2       = (const float*)d_in[9];
    const int*   key_idx   = (const int*)d_in[10];
    const int*   node_idx  = (const int*)d_in[11];
    float* out = (float*)d_out;

    const int rows  = in_sizes[10];                // 1,048,576
    const int nfeat = in_sizes[1];                 // NUM_NODES*64

    _Float16* feat16 = (_Float16*)d_ws;
    const size_t need = (size_t)nfeat * sizeof(_Float16);
    const int use_f16 = (ws_size >= need) ? 1 : 0;

    if (use_f16) {
        const int n8 = nfeat / 8;
        feat_to_f16<<<(n8 + 255) / 256, 256, 0, stream>>>(node_feat, feat16, n8);
    }

    neurtw_r21<<<GRID_MAIN, 256, 0, stream>>>(
        pos_table, node_feat, W1, b1, W2, b2, Wm1, bm1, Wm2, bm2,
        key_idx, node_idx, feat16, use_f16, out, rows);
}

// Round 13
// 153.148 us; speedup vs baseline: 2.0264x; 2.0264x over previous
//
#include <hip/hip_runtime.h>

// NeurTWs R22 = R17 VERBATIM (proven best: 55.4-55.8us steady main
// dispatch, 84 VGPR, zero spill, 3 blocks/CU). Final revert.
// Session verdict, every direction closed by measurement:
//  - 4 waves/SIMD: FIVE attempts (R11/R13/R15/R19/R21) all spilled.
//    Root cause understood at R21: launch_bounds(256,4) splits the
//    128-reg budget on the 64-reg HW allocation granule -> AGPR block
//    rounds to 64, arch capped at EXACTLY 64 (observed in all five);
//    any MFMA body with gather-pipelining state needs >64 arch ->
//    structurally unreachable.
//  - Traffic: pos16 null (R16); feat = 8 XCDs x 12.8MB L2 streaming,
//    irreducible (binning permutation >= savings; fp8 fails accuracy).
//  - Scheduling: work-steal atomics serialize (R18, 238us); grid 1024 @
//    3-resident = tail regression (R12); coalesced-store epilogue = DS
//    overhead, L2 already line-coalesces masked stores (R20); deeper
//    fA23 prefetch spills (R19).
//  - Latency hiding at 3 waves: captured by R14+R17 prefetch pipeline
//    (ndr/kk/enc cross-iter + fA01 deep) = 61 -> 55.5us. Residual =
//    VALU-issue + gather-latency equilibrium at 3 waves/SIMD.
// If this reproduces ~55-56us steady: declare roofline.
// Fragment layouts (gfx950, verified): A/B: idx=lane&15, k=(lane>>4)*8+j;
// C/D: col=lane&15, row=(lane>>4)*4+reg.

typedef _Float16 half8 __attribute__((ext_vector_type(8)));
typedef float floatx4 __attribute__((ext_vector_type(4)));

#define HSTR 40    // h/pe row stride (f16): 80 B
#define WSTR 104   // wm1t row stride (f16): 208 B
#define GRID_MAIN 768

__global__ void feat_to_f16(const float* __restrict__ nf,
                            _Float16* __restrict__ o, int n8) {
    int t = blockIdx.x * 256 + threadIdx.x;
    if (t >= n8) return;
    const float4* p = (const float4*)nf + (size_t)t * 2;
    const float4 a = p[0], b = p[1];
    half8 h;
    h[0] = (_Float16)a.x; h[1] = (_Float16)a.y;
    h[2] = (_Float16)a.z; h[3] = (_Float16)a.w;
    h[4] = (_Float16)b.x; h[5] = (_Float16)b.y;
    h[6] = (_Float16)b.z; h[7] = (_Float16)b.w;
    *((half8*)o + t) = h;
}

// load feat A-fragments for 2 row-tiles (nd0 -> fA[0], nd1 -> fA[1])
__device__ __forceinline__ void load_feat2(const _Float16* __restrict__ feat16,
                                           const float* __restrict__ node_feat,
                                           int use_f16, int nd0, int nd1, int q,
                                           half8 fA[2][2]) {
    if (use_f16) {
        const _Float16* fb0 = feat16 + (size_t)nd0 * 64 + q * 8;
        const _Float16* fb1 = feat16 + (size_t)nd1 * 64 + q * 8;
        fA[0][0] = *(const half8*)(fb0);
        fA[0][1] = *(const half8*)(fb0 + 32);
        fA[1][0] = *(const half8*)(fb1);
        fA[1][1] = *(const half8*)(fb1 + 32);
    } else {
        #pragma unroll
        for (int rr = 0; rr < 2; ++rr) {
            const float* fb = node_feat + (size_t)(rr ? nd1 : nd0) * 64 + q * 8;
            #pragma unroll
            for (int kt = 0; kt < 2; ++kt) {
                const float4 lo = *(const float4*)(fb + kt * 32);
                const float4 hi = *(const float4*)(fb + kt * 32 + 4);
                half8 h;
                h[0] = (_Float16)lo.x; h[1] = (_Float16)lo.y;
                h[2] = (_Float16)lo.z; h[3] = (_Float16)lo.w;
                h[4] = (_Float16)hi.x; h[5] = (_Float16)hi.y;
                h[6] = (_Float16)hi.z; h[7] = (_Float16)hi.w;
                fA[rr][kt] = h;
            }
        }
    }
}

__global__ __launch_bounds__(256, 3) void neurtw_r22(
    const float* __restrict__ pos_table,   // [NUM_KEYS, 4]
    const float* __restrict__ node_feat,   // [NUM_NODES, 64] fp32 (fallback)
    const float* __restrict__ W1,          // [4, 32]
    const float* __restrict__ b1,          // [32]
    const float* __restrict__ W2,          // [32, 32]
    const float* __restrict__ b2,          // [32]
    const float* __restrict__ Wm1,         // [96, 64]
    const float* __restrict__ bm1,         // [64]
    const float* __restrict__ Wm2,         // [64, 1]
    const float* __restrict__ bm2,         // [1]
    const int*   __restrict__ key_idx,     // [rows]
    const int*   __restrict__ node_idx,    // [rows]
    const _Float16* __restrict__ feat16,   // [NUM_NODES, 64] f16 (ws)
    int use_f16,
    float*       __restrict__ out,         // [rows]
    int rows)
{
    __shared__ _Float16 hpe[256 * HSTR];   // 20 KB (h then pe; wave-private)
    __shared__ _Float16 wm1t[64 * WSTR];   // 13 KB  wm1t[n][k] = Wm1[k][n]

    const int tid  = threadIdx.x;
    const int lane = tid & 63;
    const int r0   = (tid >> 6) * 64;
    const int ln   = lane & 15;
    const int q    = lane >> 4;

    // ---------- once per block: stage Wm1^T into LDS ----------
    #pragma unroll
    for (int i = 0; i < 3; ++i) {
        const int task = i * 256 + tid;
        const int n = task & 63, k8 = task >> 6;
        half8 w;
        #pragma unroll
        for (int kk = 0; kk < 8; ++kk)
            w[kk] = (_Float16)Wm1[(k8 * 8 + kk) * 64 + n];
        *(half8*)(&wm1t[n * WSTR + k8 * 8]) = w;
    }

    // ---------- once per block: per-lane weight/bias fragments ----------
    half8 b_w2[2];
    #pragma unroll
    for (int ct = 0; ct < 2; ++ct)
        #pragma unroll
        for (int j = 0; j < 8; ++j)
            b_w2[ct][j] = (_Float16)W2[(q * 8 + j) * 32 + ct * 16 + ln];
    float b2v[2];
    b2v[0] = b2[ln]; b2v[1] = b2[16 + ln];
    float bm1v[4], wm2v[4];
    #pragma unroll
    for (int ct = 0; ct < 4; ++ct) {
        bm1v[ct] = bm1[ct * 16 + ln];
        wm2v[ct] = Wm2[ct * 16 + ln];
    }
    const float bm2s = bm2[0];

    __syncthreads();   // wm1t staged (the ONLY barrier in the kernel)

    // ---------- pipeline prologue: iter-0 indices + enc + fA01 ----------
    int base = blockIdx.x * 256;
    int ndr[4];
    #pragma unroll
    for (int rt = 0; rt < 4; ++rt)
        ndr[rt] = node_idx[base + r0 + rt * 16 + ln];
    int kkc = key_idx[base + tid];
    float4 enc = *(const float4*)(pos_table + (size_t)kkc * 4);
    half8 fA01[2][2];
    load_feat2(feat16, node_feat, use_f16, ndr[0], ndr[1], q, fA01);

    while (base < rows) {
        const int nbase = base + GRID_MAIN * 256;
        const bool more = nbase < rows;

        // ---- iter top: only the rt{2,3} feat gathers (ndr resident) ----
        half8 fA23[2][2];
        load_feat2(feat16, node_feat, use_f16, ndr[2], ndr[3], q, fA23);

        // ---- next-iter independent index loads ----
        int ndr_n[4];
        int kk_n;
        if (more) {
            #pragma unroll
            for (int rt = 0; rt < 4; ++rt)
                ndr_n[rt] = node_idx[nbase + r0 + rt * 16 + ln];
            kk_n = key_idx[nbase + tid];
        } else {
            #pragma unroll
            for (int rt = 0; rt < 4; ++rt)
                ndr_n[rt] = 0;
            kk_n = 0;
        }

        // ---- GEMM1 (VALU fp32, enc already resident) -> h ----
        #pragma unroll
        for (int g = 0; g < 4; ++g) {
            half8 hv;
            #pragma unroll
            for (int j8 = 0; j8 < 8; ++j8) {
                const int j = g * 8 + j8;
                float a = fmaf(enc.w, W1[96 + j],
                          fmaf(enc.z, W1[64 + j],
                          fmaf(enc.y, W1[32 + j],
                          fmaf(enc.x, W1[j], b1[j]))));
                hv[j8] = (_Float16)fmaxf(a, 0.0f);
            }
            *(half8*)(&hpe[tid * HSTR + g * 8]) = hv;
        }
        // wave-private transpose read — no barrier (same wave wrote it)
        half8 a_h[4];
        #pragma unroll
        for (int rt = 0; rt < 4; ++rt)
            a_h[rt] = *(const half8*)(&hpe[(r0 + rt * 16 + ln) * HSTR + q * 8]);

        // ---- GEMM2: 8 MFMA -> pe (C-layout regs) ----
        floatx4 pc[4][2];
        #pragma unroll
        for (int rt = 0; rt < 4; ++rt)
            #pragma unroll
            for (int ct = 0; ct < 2; ++ct) {
                floatx4 c = {0.f, 0.f, 0.f, 0.f};
                pc[rt][ct] = __builtin_amdgcn_mfma_f32_16x16x32_f16(
                    a_h[rt], b_w2[ct], c, 0, 0, 0);
            }

        // write pe into the SAME buffer (h consumed; own wave's slice only)
        #pragma unroll
        for (int rt = 0; rt < 4; ++rt)
            #pragma unroll
            for (int ct = 0; ct < 2; ++ct)
                #pragma unroll
                for (int r = 0; r < 4; ++r)
                    hpe[(r0 + rt * 16 + q * 4 + r) * HSTR + ct * 16 + ln] =
                        (_Float16)(pc[rt][ct][r] + b2v[ct]);
        // no barrier: reader below is the same wave

        // ---- next-iter enc gather (kk_n has had GEMM1+GEMM2 to land) ----
        float4 enc_n = enc;
        if (more)
            enc_n = *(const float4*)(pos_table + (size_t)kk_n * 4);

        // ---- GEMM3: 48 MFMA ----
        floatx4 acc[4][4];
        #pragma unroll
        for (int ct = 0; ct < 4; ++ct) {
            const float bb = bm1v[ct];
            #pragma unroll
            for (int rt = 0; rt < 4; ++rt)
                acc[rt][ct] = (floatx4){bb, bb, bb, bb};
        }

        {   // ktile 0: A = pe from LDS
            half8 a_pe[4];
            #pragma unroll
            for (int rt = 0; rt < 4; ++rt)
                a_pe[rt] = *(const half8*)(&hpe[(r0 + rt * 16 + ln) * HSTR + q * 8]);
            half8 b0[4];
            #pragma unroll
            for (int ct = 0; ct < 4; ++ct)
                b0[ct] = *(const half8*)(&wm1t[(ct * 16 + ln) * WSTR + q * 8]);
            #pragma unroll
            for (int rt = 0; rt < 4; ++rt)
                #pragma unroll
                for (int ct = 0; ct < 4; ++ct)
                    acc[rt][ct] = __builtin_amdgcn_mfma_f32_16x16x32_f16(
                        a_pe[rt], b0[ct], acc[rt][ct], 0, 0, 0);
        }

        #pragma unroll
        for (int kt = 0; kt < 2; ++kt) {   // ktiles 1,2: A = feat
            half8 bk[4];
            #pragma unroll
            for (int ct = 0; ct < 4; ++ct)
                bk[ct] = *(const half8*)(&wm1t[(ct * 16 + ln) * WSTR + 32 + kt * 32 + q * 8]);
            #pragma unroll
            for (int ct = 0; ct < 4; ++ct) {
                acc[0][ct] = __builtin_amdgcn_mfma_f32_16x16x32_f16(
                    fA01[0][kt], bk[ct], acc[0][ct], 0, 0, 0);
                acc[1][ct] = __builtin_amdgcn_mfma_f32_16x16x32_f16(
                    fA01[1][kt], bk[ct], acc[1][ct], 0, 0, 0);
                acc[2][ct] = __builtin_amdgcn_mfma_f32_16x16x32_f16(
                    fA23[0][kt], bk[ct], acc[2][ct], 0, 0, 0);
                acc[3][ct] = __builtin_amdgcn_mfma_f32_16x16x32_f16(
                    fA23[1][kt], bk[ct], acc[3][ct], 0, 0, 0);
            }
        }

        // ---- fA consumed: prefetch NEXT-iter fA01 (rt 0,1) now ----
        // ndr_n arrived ~1500cy ago; cover = GEMM4 + next GEMM1/2 ~1800cy.
        half8 fA01_n[2][2];
        load_feat2(feat16, node_feat, use_f16, ndr_n[0], ndr_n[1], q, fA01_n);

        // ---- GEMM4: relu + Wm2 dot + 4-step butterfly + store ----
        #pragma unroll
        for (int rt = 0; rt < 4; ++rt) {
            #pragma unroll
            for (int r = 0; r < 4; ++r) {
                float p = 0.0f;
                #pragma unroll
                for (int ct = 0; ct < 4; ++ct)
                    p = fmaf(fmaxf(acc[rt][ct][r], 0.0f), wm2v[ct], p);
                p += __shfl_xor(p, 1);
                p += __shfl_xor(p, 2);
                p += __shfl_xor(p, 4);
                p += __shfl_xor(p, 8);
                if (ln == 0)
                    out[base + r0 + rt * 16 + q * 4 + r] = p + bm2s;
            }
        }

        // ---- rotate pipeline state ----
        base = nbase;
        #pragma unroll
        for (int rt = 0; rt < 4; ++rt)
            ndr[rt] = ndr_n[rt];
        kkc = kk_n;
        enc = enc_n;
        #pragma unroll
        for (int rr = 0; rr < 2; ++rr)
            #pragma unroll
            for (int kt = 0; kt < 2; ++kt)
                fA01[rr][kt] = fA01_n[rr][kt];
    }
}

extern "C" void kernel_launch(void* const* d_in, const int* in_sizes, int n_in,
                              void* d_out, int out_size, void* d_ws, size_t ws_size,
                              hipStream_t stream) {
    const float* pos_table = (const float*)d_in[0];
    const float* node_feat = (const float*)d_in[1];
    const float* W1        = (const float*)d_in[2];
    const float* b1        = (const float*)d_in[3];
    const float* W2        = (const float*)d_in[4];
    const float* b2        = (const float*)d_in[5];
    const float* Wm1       = (const float*)d_in[6];
    const float* bm1       = (const float*)d_in[7];
    const float* Wm2       = (const float*)d_in[8];
    const float* bm2       = (const float*)d_in[9];
    const int*   key_idx   = (const int*)d_in[10];
    const int*   node_idx  = (const int*)d_in[11];
    float* out = (float*)d_out;

    const int rows  = in_sizes[10];                // 1,048,576
    const int nfeat = in_sizes[1];                 // NUM_NODES*64

    _Float16* feat16 = (_Float16*)d_ws;
    const size_t need = (size_t)nfeat * sizeof(_Float16);
    const int use_f16 = (ws_size >= need) ? 1 : 0;

    if (use_f16) {
        const int n8 = nfeat / 8;
        feat_to_f16<<<(n8 + 255) / 256, 256, 0, stream>>>(node_feat, feat16, n8);
    }

    neurtw_r22<<<GRID_MAIN, 256, 0, stream>>>(
        pos_table, node_feat, W1, b1, W2, b2, Wm1, bm1, Wm2, bm2,
        key_idx, node_idx, feat16, use_f16, out, rows);
}